// Round 9
// baseline (233.302 us; speedup 1.0000x reference)
//
#include <hip/hip_runtime.h>
#include <hip/hip_bf16.h>

// MLPDecoder: scores[e] = relu((h[src]*h[dst]) @ W1 + b1) @ W2 + b2
// E=300000, D=256. bf16 MFMA, 1-barrier/iter pipeline.
// R1: grid bump: NEUTRAL. R2 FAILED: lb(512,8) spill. R3 NEUTRAL.
// R4 NEUTRAL: lgkm-only barrier + MFMA-first (enables vmcnt-crossing).
// R5 FAILED: 64-col waves lb(256,4) -> clamp/spill, 207us.
// R6 WIN: 64-col waves + lb(256,2): 64.2us. VGPR 120, MfmaUtil 25%.
// R7 ABLATION: staging-only = 2.26us/tile (fetch path 3.35 TB/s);
// V0 = 3.46us/tile. Deficit = had() vmcnt stall: loads issued only 1
// iter ahead get ~1.2us cover < 2.26us fetch service time.
// R8 REGRESSION: GRID 1024 (J 19->10): 70.2us — worse amortization of
// per-block overhead; Occ metric unreliable (gfx94x fallback formula).
// R9: revert to GRID 512/MAXJ 19 + DEPTH-2 reg prefetch (sets A/B):
// iter j consumes set par^1 (tile j+1), refills with tile j+3 -> ~2
// iters of flight per gather. +32 VGPR under lb(256,2). Pred: WRITE
// stays 1.17MB (spill=abort), dur 64->~50-56us, MfmaUtil ~30%.

#define E_EDGES 300000
#define DIM 256
#define MT 32                    // edges per block-iteration
#define NTILES (E_EDGES / MT)    // 9375
#define BLK 256                  // 4 waves; each wave owns 64 N-cols
#define GRID_MAIN 512            // 2 blocks/CU
#define MAXJ 19                  // ceil(9375/512)

typedef short bf16x8 __attribute__((ext_vector_type(8)));
typedef float f32x4 __attribute__((ext_vector_type(4)));

__device__ __forceinline__ ushort f2bf(float f) {
    union { float f; unsigned u; } v; v.f = f;
    unsigned r = v.u + 0x7FFFu + ((v.u >> 16) & 1u);  // RNE
    return (ushort)(r >> 16);
}

// Barrier that does NOT drain vmcnt (LDS producers covered by lgkmcnt(0)).
__device__ __forceinline__ void barrier_lgkm() {
    asm volatile("s_waitcnt lgkmcnt(0)" ::: "memory");
    asm volatile("s_barrier" ::: "memory");
}

// W1 fp32 [K=256][N=256] -> W1^T bf16 [N][K]
__global__ void prep_w1t(const float* __restrict__ w1, ushort* __restrict__ w1t) {
    int idx = blockIdx.x * 256 + threadIdx.x;
    int k = idx >> 8, n = idx & 255;
    w1t[n * 256 + k] = f2bf(w1[k * 256 + n]);
}

// h fp32 -> bf16
__global__ void prep_hbf(const float* __restrict__ h, ushort* __restrict__ hbf) {
    int i = blockIdx.x * 256 + threadIdx.x;
    const float4* src = (const float4*)h + (size_t)i * 2;
    float4 a = src[0], b = src[1];
    union { ushort s[8]; uint4 v; } o;
    o.s[0] = f2bf(a.x); o.s[1] = f2bf(a.y); o.s[2] = f2bf(a.z); o.s[3] = f2bf(a.w);
    o.s[4] = f2bf(b.x); o.s[5] = f2bf(b.y); o.s[6] = f2bf(b.z); o.s[7] = f2bf(b.w);
    ((uint4*)hbf)[i] = o.v;
}

__global__ __launch_bounds__(BLK, 2)
void decoder(const ushort* __restrict__ hbf, const int2* __restrict__ edges,
             const ushort* __restrict__ w1t, const float* __restrict__ b1,
             const float* __restrict__ w2, const float* __restrict__ b2p,
             float* __restrict__ out) {
    __shared__ ushort xlds[2][MT][264];   // 33.8 KB
    __shared__ float part[2][4][MT];      // 1 KB
    __shared__ int2 eld[MAXJ * MT];       // 4.9 KB

    const int t = threadIdx.x;
    const int w = t >> 6, lane = t & 63, quad = lane >> 4, l15 = lane & 15;
    const int bx = blockIdx.x, gdim = gridDim.x;
    const int J = (NTILES - bx + gdim - 1) / gdim;   // 18 or 19 tiles

    bf16x8 Bf[4][8];   // wave w owns N cols [64w, 64w+64)
#pragma unroll
    for (int nt = 0; nt < 4; ++nt) {
        int n = w * 64 + nt * 16 + l15;
#pragma unroll
        for (int ks = 0; ks < 8; ++ks)
            Bf[nt][ks] = *(const bf16x8*)(w1t + n * 256 + ks * 32 + quad * 8);
    }
    float b1v[4], w2v[4];
#pragma unroll
    for (int nt = 0; nt < 4; ++nt) {
        int n = w * 64 + nt * 16 + l15;
        b1v[nt] = b1[n];
        w2v[nt] = w2[n];
    }
    const float b2v = b2p[0];

    for (int idx = t; idx < J * MT; idx += BLK)
        eld[idx] = edges[(size_t)(bx + (idx >> 5) * gdim) * MT + (idx & 31)];
    __syncthreads();

    const int sm = t >> 3;     // edge row in tile 0..31
    const int sc = t & 7;      // 64B chunk in row

    // depth-2 prefetch: two named register sets (A, B). Tile t lives in
    // set t&1. All names static -> no dynamic-index spill (rule #20).
    uint4 sA0, sA1, sA2, sA3, dA0, dA1, dA2, dA3;
    uint4 sB0, sB1, sB2, sB3, dB0, dB1, dB2, dB3;

    auto issueA = [&](int j) {
        int2 ed = eld[j * MT + sm];
        const uint4* ps = (const uint4*)(hbf + (size_t)ed.x * DIM) + sc * 4;
        const uint4* pd = (const uint4*)(hbf + (size_t)ed.y * DIM) + sc * 4;
        sA0 = ps[0]; sA1 = ps[1]; sA2 = ps[2]; sA3 = ps[3];
        dA0 = pd[0]; dA1 = pd[1]; dA2 = pd[2]; dA3 = pd[3];
    };
    auto issueB = [&](int j) {
        int2 ed = eld[j * MT + sm];
        const uint4* ps = (const uint4*)(hbf + (size_t)ed.x * DIM) + sc * 4;
        const uint4* pd = (const uint4*)(hbf + (size_t)ed.y * DIM) + sc * 4;
        sB0 = ps[0]; sB1 = ps[1]; sB2 = ps[2]; sB3 = ps[3];
        dB0 = pd[0]; dB1 = pd[1]; dB2 = pd[2]; dB3 = pd[3];
    };
    auto mul8 = [](uint4 a, uint4 b) -> uint4 {
        union U { uint4 v; __hip_bfloat162 h[4]; } ua, ub, o;
        ua.v = a; ub.v = b;
#pragma unroll
        for (int q = 0; q < 4; ++q) o.h[q] = __hmul2(ua.h[q], ub.h[q]);
        return o.v;
    };
    auto hadA = [&](int buf) {
        uint4* dst = (uint4*)&xlds[buf][sm][sc * 32];
        dst[0] = mul8(sA0, dA0);
        dst[1] = mul8(sA1, dA1);
        dst[2] = mul8(sA2, dA2);
        dst[3] = mul8(sA3, dA3);
    };
    auto hadB = [&](int buf) {
        uint4* dst = (uint4*)&xlds[buf][sm][sc * 32];
        dst[0] = mul8(sB0, dB0);
        dst[1] = mul8(sB1, dB1);
        dst[2] = mul8(sB2, dB2);
        dst[3] = mul8(sB3, dB3);
    };
    auto finalize = [&](int j, int par) {
        if (t < MT) {
            float s = b2v;
#pragma unroll
            for (int ww = 0; ww < 4; ++ww) s += part[par][ww][t];
            out[(size_t)(bx + j * gdim) * MT + t] = s;
        }
    };

    // prologue: tile0 -> set A -> xlds[0]; tile1 -> B; tile2 -> A
    issueA(0);
    hadA(0);
    if (J > 1) issueB(1);
    if (J > 2) issueA(2);

    for (int j = 0; j < J; ++j) {
        const int par = j & 1;
        barrier_lgkm();                   // does NOT drain vmcnt
        if (j > 0) finalize(j - 1, par ^ 1);

        // ---- MFMA on tile j from xlds[par] (gathers for j+2,j+3 in flight)
        f32x4 acc[2][4];
#pragma unroll
        for (int ms = 0; ms < 2; ++ms)
#pragma unroll
            for (int nt = 0; nt < 4; ++nt)
                acc[ms][nt] = (f32x4){0.f, 0.f, 0.f, 0.f};
        const ushort* xb = &xlds[par][0][0];
#pragma unroll
        for (int ks = 0; ks < 8; ++ks) {
            int kb = ks * 32 + quad * 8;
            bf16x8 a0 = *(const bf16x8*)(xb + l15 * 264 + kb);
            bf16x8 a1 = *(const bf16x8*)(xb + (16 + l15) * 264 + kb);
#pragma unroll
            for (int nt = 0; nt < 4; ++nt) {
                acc[0][nt] = __builtin_amdgcn_mfma_f32_16x16x32_bf16(a0, Bf[nt][ks], acc[0][nt], 0, 0, 0);
                acc[1][nt] = __builtin_amdgcn_mfma_f32_16x16x32_bf16(a1, Bf[nt][ks], acc[1][nt], 0, 0, 0);
            }
        }
        // epilogue: relu(hid+b1).w2, butterfly over 16 n-lanes
        float red[2][4];
#pragma unroll
        for (int ms = 0; ms < 2; ++ms)
#pragma unroll
            for (int r = 0; r < 4; ++r) {
                float s = 0.f;
#pragma unroll
                for (int nt = 0; nt < 4; ++nt)
                    s += fmaxf(acc[ms][nt][r] + b1v[nt], 0.f) * w2v[nt];
                red[ms][r] = s;
            }
#pragma unroll
        for (int mask = 1; mask <= 8; mask <<= 1)
#pragma unroll
            for (int ms = 0; ms < 2; ++ms)
#pragma unroll
                for (int r = 0; r < 4; ++r)
                    red[ms][r] += __shfl_xor(red[ms][r], mask);
        if (l15 == 0)
#pragma unroll
            for (int ms = 0; ms < 2; ++ms)
#pragma unroll
                for (int r = 0; r < 4; ++r)
                    part[par][w][ms * 16 + quad * 4 + r] = red[ms][r];

        // ---- consume tile j+1 (set par^1), refill with tile j+3 ----
        if (par == 0) {
            if (j + 1 < J) hadB(par ^ 1);     // tile j+1 is odd -> set B
            if (j + 3 < J) issueB(j + 3);
        } else {
            if (j + 1 < J) hadA(par ^ 1);     // tile j+1 is even -> set A
            if (j + 3 < J) issueA(j + 3);
        }
    }

    __syncthreads();
    finalize(J - 1, (J - 1) & 1);
}

// fp32-gather fallback (only if ws too small for hbf; not expected to run)
__global__ __launch_bounds__(512, 4)
void decoder_f32(const float* __restrict__ h, const int2* __restrict__ edges,
                 const ushort* __restrict__ w1t, const float* __restrict__ b1,
                 const float* __restrict__ w2, const float* __restrict__ b2p,
                 float* __restrict__ out) {
    __shared__ ushort xlds[MT][264];
    __shared__ float part[8][MT];
    const int t = threadIdx.x;
    const int w = t >> 6, lane = t & 63, quad = lane >> 4, l15 = lane & 15;
    bf16x8 Bf[2][8];
#pragma unroll
    for (int nt = 0; nt < 2; ++nt)
#pragma unroll
        for (int ks = 0; ks < 8; ++ks)
            Bf[nt][ks] = *(const bf16x8*)(w1t + (w * 32 + nt * 16 + l15) * 256 + ks * 32 + quad * 8);
    float b1v[2], w2v[2];
#pragma unroll
    for (int nt = 0; nt < 2; ++nt) {
        b1v[nt] = b1[w * 32 + nt * 16 + l15];
        w2v[nt] = w2[w * 32 + nt * 16 + l15];
    }
    const float b2v = b2p[0];
    const int sm = t >> 4, sc = t & 15;
    for (int mb = blockIdx.x; mb < NTILES; mb += gridDim.x) {
        int2 ed = edges[mb * MT + sm];
        const float4* ps = (const float4*)(h + (size_t)ed.x * DIM) + sc * 4;
        const float4* pd = (const float4*)(h + (size_t)ed.y * DIM) + sc * 4;
        union { ushort s[16]; uint4 v[2]; } o;
#pragma unroll
        for (int jj = 0; jj < 4; ++jj) {
            float4 a = ps[jj], b = pd[jj];
            o.s[4 * jj + 0] = f2bf(a.x * b.x); o.s[4 * jj + 1] = f2bf(a.y * b.y);
            o.s[4 * jj + 2] = f2bf(a.z * b.z); o.s[4 * jj + 3] = f2bf(a.w * b.w);
        }
        uint4* dst = (uint4*)&xlds[sm][sc * 16];
        dst[0] = o.v[0]; dst[1] = o.v[1];
        __syncthreads();
        f32x4 acc[2][2];
#pragma unroll
        for (int ms = 0; ms < 2; ++ms)
#pragma unroll
            for (int nt = 0; nt < 2; ++nt) acc[ms][nt] = (f32x4){0.f,0.f,0.f,0.f};
#pragma unroll
        for (int ks = 0; ks < 8; ++ks) {
            int kb = ks * 32 + quad * 8;
            bf16x8 a0 = *(const bf16x8*)&xlds[l15][kb];
            bf16x8 a1 = *(const bf16x8*)&xlds[16 + l15][kb];
#pragma unroll
            for (int nt = 0; nt < 2; ++nt) {
                acc[0][nt] = __builtin_amdgcn_mfma_f32_16x16x32_bf16(a0, Bf[nt][ks], acc[0][nt], 0, 0, 0);
                acc[1][nt] = __builtin_amdgcn_mfma_f32_16x16x32_bf16(a1, Bf[nt][ks], acc[1][nt], 0, 0, 0);
            }
        }
        float red[2][4];
#pragma unroll
        for (int ms = 0; ms < 2; ++ms)
#pragma unroll
            for (int r = 0; r < 4; ++r) {
                float s = 0.f;
#pragma unroll
                for (int nt = 0; nt < 2; ++nt)
                    s += fmaxf(acc[ms][nt][r] + b1v[nt], 0.f) * w2v[nt];
                red[ms][r] = s;
            }
#pragma unroll
        for (int mask = 1; mask <= 8; mask <<= 1)
#pragma unroll
            for (int ms = 0; ms < 2; ++ms)
#pragma unroll
                for (int r = 0; r < 4; ++r)
                    red[ms][r] += __shfl_xor(red[ms][r], mask);
        if (l15 == 0)
#pragma unroll
            for (int ms = 0; ms < 2; ++ms)
#pragma unroll
                for (int r = 0; r < 4; ++r)
                    part[w][ms * 16 + quad * 4 + r] = red[ms][r];
        __syncthreads();
        if (t < MT) {
            float s = b2v;
#pragma unroll
            for (int ww = 0; ww < 8; ++ww) s += part[ww][t];
            out[mb * MT + t] = s;
        }
    }
}

extern "C" void kernel_launch(void* const* d_in, const int* in_sizes, int n_in,
                              void* d_out, int out_size, void* d_ws, size_t ws_size,
                              hipStream_t stream) {
    const float* h     = (const float*)d_in[0];
    const int2*  edges = (const int2*)d_in[1];
    const float* W1    = (const float*)d_in[2];
    const float* b1    = (const float*)d_in[3];
    const float* W2    = (const float*)d_in[4];
    const float* b2    = (const float*)d_in[5];
    float* out = (float*)d_out;

    ushort* w1t = (ushort*)d_ws;                     // 128 KB
    ushort* hbf = (ushort*)((char*)d_ws + 131072);   // 51.2 MB

    prep_w1t<<<256, 256, 0, stream>>>(W1, w1t);
    if (ws_size >= 131072 + (size_t)25600000 * 2) {
        prep_hbf<<<12500, 256, 0, stream>>>(h, hbf);
        decoder<<<GRID_MAIN, BLK, 0, stream>>>(hbf, edges, w1t, b1, W2, b2, out);
    } else {
        decoder_f32<<<512, 512, 0, stream>>>(h, edges, w1t, b1, W2, b2, out);
    }
}